// Round 6
// baseline (528.380 us; speedup 1.0000x reference)
//
#include <hip/hip_runtime.h>

#define HH 512
#define WW 512
#define SS (HH * WW)          // elements per plane (2^18)
#define P16N (16 * SS)        // 16 planes (2^22)
#define PADW 576              // skewed LDS row: addr(j) = j + (j>>3)

constexpr float FINF = 3.402823466e38f;

__device__ __forceinline__ int swz(int j) { return j + (j >> 3); }

__device__ __forceinline__ float gray1(float r, float g, float b) {
    return 0.299f * r + 0.587f * g + 0.114f * b;
}

// inverse of small integer c in [R+1, 2R+1] without v_div (cmp+cndmask chain)
template <int R>
__device__ __forceinline__ float invsmall(int c) {
    float r = 1.f / (float)(2 * R + 1);
    #pragma unroll
    for (int v = R + 1; v < 2 * R + 1; ++v)
        if (c == v) r = 1.f / (float)v;      // compile-time constants
    return r;
}

// ---------------- grad (gray fused, both dirs, 4 px/thread) ----------------
__global__ __launch_bounds__(256) void grad_both(const float* __restrict__ rgb,
                                                 float* __restrict__ dst,
                                                 int gxp0, int gyp0, int dirsel) {
    int sp = blockIdx.x * 256 + threadIdx.x;
    int idx = sp << 2;                             // [0, P16N)
    int img = idx >> 18;
    int pix = idx & (SS - 1);
    int i = pix >> 9, j0 = pix & (WW - 1);
    const float* p0 = rgb + (size_t)img * 3 * SS + pix;

    float4 r = *(const float4*)p0;
    float4 g = *(const float4*)(p0 + SS);
    float4 b = *(const float4*)(p0 + 2 * SS);
    float4 gy4 = make_float4(gray1(r.x, g.x, b.x), gray1(r.y, g.y, b.y),
                             gray1(r.z, g.z, b.z), gray1(r.w, g.w, b.w));
    if (dirsel != 1) {
        float grs = 0.f;
        if (j0 + 4 < WW) grs = gray1(p0[4], p0[SS + 4], p0[2 * SS + 4]);
        float4 gx = make_float4(gy4.x - gy4.y, gy4.y - gy4.z, gy4.z - gy4.w, gy4.w - grs);
        *(float4*)(dst + (size_t)(gxp0 + img) * SS + pix) = gx;
    }
    if (dirsel != 0) {
        float4 gd = make_float4(0.f, 0.f, 0.f, 0.f);
        if (i < HH - 1) {
            float4 r2 = *(const float4*)(p0 + WW);
            float4 g2 = *(const float4*)(p0 + SS + WW);
            float4 b2 = *(const float4*)(p0 + 2 * SS + WW);
            gd = make_float4(gray1(r2.x, g2.x, b2.x), gray1(r2.y, g2.y, b2.y),
                             gray1(r2.z, g2.z, b2.z), gray1(r2.w, g2.w, b2.w));
        }
        float4 gy = make_float4(gy4.x - gd.x, gy4.y - gd.y, gy4.z - gd.z, gy4.w - gd.w);
        *(float4*)(dst + (size_t)(gyp0 + img) * SS + pix) = gy;
    }
}

// ---------------- dual max+min pool, SUB-PHASED ----------------
// TH=16 tile (round-1 traffic) streamed through an 8-row LDS window (18 KB ->
// 6 blocks/CU at launch_bounds(256,6) = 24 waves/CU). Ring rb[W] carries the
// vertical window across sub-phases in registers. Exact wrap-counted validity
// mask (verified absmax 0, rounds 4-5). Vertical max -> LDS, min -> regs;
// horizontal max -> dmax; swap; horizontal min -> dmin; next 8 rows.
template <bool PREABS, int R, int TH, int SUB>
__global__ __launch_bounds__(256, 6) void dual_pool(const float* __restrict__ src,
                                                    float* __restrict__ dmax,
                                                    float* __restrict__ dmin) {
    constexpr int TILES = HH / TH;
    constexpr int W = 2 * R + 1;
    constexpr int NSP = TH / SUB;                  // sub-phases
    constexpr int NSH = (SUB * 64) / 256;          // horizontal slices per sub-phase
    __shared__ float lbuf[SUB * PADW];

    const int plane = blockIdx.x / TILES;
    const int tile  = blockIdx.x % TILES;
    const int i0    = tile * TH;
    const size_t pbase = (size_t)plane * SS;
    const float* sp = src + pbase;
    const int t = threadIdx.x;
    const int ca = swz(2 * t);                     // ca+1 == swz(2t+1)

    float2 rb[W];
    float2 keepmn[SUB];
    auto ld = [&](int gi) -> float2 {
        float2 u = ((const float2*)(sp + (size_t)gi * WW))[t];
        if (PREABS) { u.x = fabsf(u.x); u.y = fabsf(u.y); }
        return u;
    };
    #pragma unroll
    for (int k = 0; k < W; ++k)
        if ((unsigned)(i0 - R + k) < (unsigned)HH) rb[k] = ld(i0 - R + k);

    #pragma unroll
    for (int p = 0; p < NSP; ++p) {
        if (p > 0) __syncthreads();                // lbuf free (prev hmin done)
        // vertical stage: rows p*SUB .. p*SUB+SUB-1
        #pragma unroll
        for (int q = 0; q < SUB; ++q) {
            const int oi = p * SUB + q;            // compile-time
            if (oi > 0) {
                if ((unsigned)(i0 + oi + R) < (unsigned)HH) rb[(oi - 1) % W] = ld(i0 + oi + R);
            }
            float2 mx = make_float2(-FINF, -FINF), mn = make_float2(FINF, FINF);
            #pragma unroll
            for (int k = 0; k < W; ++k) {
                int wrap = (oi > k) ? ((oi - 1 - k) / W + 1) : 0;   // compile-time
                int ro = k - R + wrap * W;                          // exact row in slot k
                if ((unsigned)(i0 + ro) < (unsigned)HH) {           // block-uniform
                    mx.x = fmaxf(mx.x, rb[k].x); mx.y = fmaxf(mx.y, rb[k].y);
                    mn.x = fminf(mn.x, rb[k].x); mn.y = fminf(mn.y, rb[k].y);
                }
            }
            lbuf[q * PADW + ca] = mx.x; lbuf[q * PADW + ca + 1] = mx.y;
            keepmn[q] = mn;
        }
        __syncthreads();

        // horizontal max -> dmax
        #pragma unroll
        for (int si = 0; si < NSH; ++si) {
            int s = si * 256 + t;
            int rr = s >> 6, j0 = (s & 63) << 3;
            const float* rx = &lbuf[rr * PADW];
            float vx[2 * R + 8];
            #pragma unroll
            for (int k = 0; k < 2 * R + 8; ++k) {
                int jj = j0 - R + k;
                bool ok = (unsigned)jj < (unsigned)WW;
                int jc = swz(min(max(jj, 0), WW - 1));
                vx[k] = ok ? rx[jc] : -FINF;
            }
            float ox[8];
            #pragma unroll
            for (int d = 0; d < 8; ++d) {
                float mx = vx[d];
                #pragma unroll
                for (int k = 1; k <= 2 * R; ++k) mx = fmaxf(mx, vx[d + k]);
                ox[d] = mx;
            }
            size_t o = pbase + (size_t)(i0 + p * SUB + rr) * WW + j0;
            ((float4*)&dmax[o])[0] = make_float4(ox[0], ox[1], ox[2], ox[3]);
            ((float4*)&dmax[o])[1] = make_float4(ox[4], ox[5], ox[6], ox[7]);
        }
        __syncthreads();

        #pragma unroll
        for (int q = 0; q < SUB; ++q) {
            lbuf[q * PADW + ca] = keepmn[q].x;
            lbuf[q * PADW + ca + 1] = keepmn[q].y;
        }
        __syncthreads();

        // horizontal min -> dmin
        #pragma unroll
        for (int si = 0; si < NSH; ++si) {
            int s = si * 256 + t;
            int rr = s >> 6, j0 = (s & 63) << 3;
            const float* rn = &lbuf[rr * PADW];
            float vn[2 * R + 8];
            #pragma unroll
            for (int k = 0; k < 2 * R + 8; ++k) {
                int jj = j0 - R + k;
                bool ok = (unsigned)jj < (unsigned)WW;
                int jc = swz(min(max(jj, 0), WW - 1));
                vn[k] = ok ? rn[jc] : FINF;
            }
            float on[8];
            #pragma unroll
            for (int d = 0; d < 8; ++d) {
                float mn = vn[d];
                #pragma unroll
                for (int k = 1; k <= 2 * R; ++k) mn = fminf(mn, vn[d + k]);
                on[d] = mn;
            }
            size_t o = pbase + (size_t)(i0 + p * SUB + rr) * WW + j0;
            ((float4*)&dmin[o])[0] = make_float4(on[0], on[1], on[2], on[3]);
            ((float4*)&dmin[o])[1] = make_float4(on[4], on[5], on[6], on[7]);
        }
    }
}

// ---------------- single avg pool (abs output), SUB-PHASED, division-free ----------------
template <int R, int TH, int SUB>
__global__ __launch_bounds__(256, 6) void avg_abs_pool(const float* __restrict__ src,
                                                       float* __restrict__ dst) {
    constexpr int TILES = HH / TH;
    constexpr int NSP = TH / SUB;
    constexpr int NSH = (SUB * 64) / 256;
    __shared__ float ls[SUB * PADW];
    const int plane = blockIdx.x / TILES;
    const int tile  = blockIdx.x % TILES;
    const int i0    = tile * TH;
    const size_t pbase = (size_t)plane * SS;
    const float* sp = src + pbase;
    const int t = threadIdx.x;
    const int ca = swz(2 * t);

    auto ld = [&](int gi) -> float2 {
        if ((unsigned)gi < (unsigned)HH) return ((const float2*)(sp + (size_t)gi * WW))[t];
        return make_float2(0.f, 0.f);
    };
    float2 acc = make_float2(0.f, 0.f);

    #pragma unroll
    for (int p = 0; p < NSP; ++p) {
        if (p > 0) __syncthreads();
        #pragma unroll
        for (int q = 0; q < SUB; ++q) {
            const int oi = p * SUB + q;
            if (oi == 0) {
                #pragma unroll
                for (int k = -R; k <= R; ++k) { float2 v = ld(i0 + k); acc.x += v.x; acc.y += v.y; }
            } else {
                float2 a = ld(i0 + oi + R), s = ld(i0 + oi - R - 1);
                acc.x += a.x - s.x; acc.y += a.y - s.y;
            }
            ls[q * PADW + ca] = acc.x; ls[q * PADW + ca + 1] = acc.y;
        }
        __syncthreads();

        #pragma unroll
        for (int si = 0; si < NSH; ++si) {
            int s = si * 256 + t;
            int rr = s >> 6, j0 = (s & 63) << 3;
            int i = i0 + p * SUB + rr;
            int ch = min(i + R, HH - 1) - max(i - R, 0) + 1;
            float invch = invsmall<R>(ch);
            const float* row = &ls[rr * PADW];
            int lo = max(j0 - R, 0), hi = min(j0 + R, WW - 1);
            float racc = 0.f;
            for (int jj = lo; jj <= hi; ++jj) racc += row[swz(jj)];
            float ov[8];
            #pragma unroll
            for (int d = 0; d < 8; ++d) {
                if (d > 0) {
                    int add = j0 + d + R, sub = j0 + d - R - 1;
                    if (add < WW) racc += row[swz(add)];
                    if (sub >= 0) racc -= row[swz(sub)];
                }
                int j = j0 + d;
                int cw = min(j + R, WW - 1) - max(j - R, 0) + 1;
                ov[d] = fabsf(racc * (invch * invsmall<R>(cw)));
            }
            float4* d4 = (float4*)&dst[pbase + (size_t)i * WW + j0];
            d4[0] = make_float4(ov[0], ov[1], ov[2], ov[3]);
            d4[1] = make_float4(ov[4], ov[5], ov[6], ov[7]);
        }
    }
}

// ---------------- dual-input avg pool + combining epilogue, SUB-PHASED ----------------
// v1 = avg(s1), v2 = avg(s2). Division-free form (num & den scaled by ch*cw):
// EPI 1 (gn1): out = (|e1|*chcw - racc2)/(|racc1 - racc2| + 1e-4*chcw)
// EPI 2 (map): out = ((e1*chcw - racc2)/(|racc1 - racc2| + 1e-4*chcw) + 0.01)*e2
// Pass A (s1) and pass B (s2) each stream TH rows through the SUB-row LDS
// window; keep1 holds A's raw horizontal sums. dst may alias e1/e2.
template <int R, int EPI, int TH, int SUB>
__global__ __launch_bounds__(256, 6) void davg_pool(const float* __restrict__ s1,
                                                    const float* __restrict__ s2,
                                                    const float* __restrict__ e1,
                                                    const float* __restrict__ e2,
                                                    float* __restrict__ dst) {
    constexpr int TILES = HH / TH;
    constexpr int NSP = TH / SUB;
    constexpr int NSH = (SUB * 64) / 256;
    __shared__ float lbuf[SUB * PADW];
    const int plane = blockIdx.x / TILES;
    const int tile  = blockIdx.x % TILES;
    const int i0    = tile * TH;
    const size_t pbase = (size_t)plane * SS;
    const int t = threadIdx.x;
    const int ca = swz(2 * t);

    float keep1[NSP * NSH * 8];                    // raw horizontal sums of s1

    // ---- pass A: s1 ----
    {
        const float* sp = s1 + pbase;
        auto ld = [&](int gi) -> float2 {
            if ((unsigned)gi < (unsigned)HH) return ((const float2*)(sp + (size_t)gi * WW))[t];
            return make_float2(0.f, 0.f);
        };
        float2 acc = make_float2(0.f, 0.f);
        #pragma unroll
        for (int p = 0; p < NSP; ++p) {
            if (p > 0) __syncthreads();
            #pragma unroll
            for (int q = 0; q < SUB; ++q) {
                const int oi = p * SUB + q;
                if (oi == 0) {
                    #pragma unroll
                    for (int k = -R; k <= R; ++k) { float2 v = ld(i0 + k); acc.x += v.x; acc.y += v.y; }
                } else {
                    float2 a = ld(i0 + oi + R), s = ld(i0 + oi - R - 1);
                    acc.x += a.x - s.x; acc.y += a.y - s.y;
                }
                lbuf[q * PADW + ca] = acc.x; lbuf[q * PADW + ca + 1] = acc.y;
            }
            __syncthreads();
            #pragma unroll
            for (int si = 0; si < NSH; ++si) {
                int s = si * 256 + t;
                int rr = s >> 6, j0 = (s & 63) << 3;
                const float* row = &lbuf[rr * PADW];
                int lo = max(j0 - R, 0), hi = min(j0 + R, WW - 1);
                float racc = 0.f;
                for (int jj = lo; jj <= hi; ++jj) racc += row[swz(jj)];
                #pragma unroll
                for (int d = 0; d < 8; ++d) {
                    if (d > 0) {
                        int add = j0 + d + R, sub = j0 + d - R - 1;
                        if (add < WW) racc += row[swz(add)];
                        if (sub >= 0) racc -= row[swz(sub)];
                    }
                    keep1[(p * NSH + si) * 8 + d] = racc;
                }
            }
        }
    }
    __syncthreads();

    // ---- pass B: s2 + epilogue ----
    {
        const float* sp = s2 + pbase;
        auto ld = [&](int gi) -> float2 {
            if ((unsigned)gi < (unsigned)HH) return ((const float2*)(sp + (size_t)gi * WW))[t];
            return make_float2(0.f, 0.f);
        };
        float2 acc = make_float2(0.f, 0.f);
        #pragma unroll
        for (int p = 0; p < NSP; ++p) {
            if (p > 0) __syncthreads();
            #pragma unroll
            for (int q = 0; q < SUB; ++q) {
                const int oi = p * SUB + q;
                if (oi == 0) {
                    #pragma unroll
                    for (int k = -R; k <= R; ++k) { float2 v = ld(i0 + k); acc.x += v.x; acc.y += v.y; }
                } else {
                    float2 a = ld(i0 + oi + R), s = ld(i0 + oi - R - 1);
                    acc.x += a.x - s.x; acc.y += a.y - s.y;
                }
                lbuf[q * PADW + ca] = acc.x; lbuf[q * PADW + ca + 1] = acc.y;
            }
            __syncthreads();
            #pragma unroll
            for (int si = 0; si < NSH; ++si) {
                int s = si * 256 + t;
                int rr = s >> 6, j0 = (s & 63) << 3;
                int i = i0 + p * SUB + rr;
                int ch = min(i + R, HH - 1) - max(i - R, 0) + 1;
                const float* row = &lbuf[rr * PADW];
                size_t rowbase = pbase + (size_t)i * WW + j0;

                float e1v[8], e2v[8];
                {
                    float4 a0 = ((const float4*)(e1 + rowbase))[0];
                    float4 a1q = ((const float4*)(e1 + rowbase))[1];
                    e1v[0]=a0.x; e1v[1]=a0.y; e1v[2]=a0.z; e1v[3]=a0.w;
                    e1v[4]=a1q.x; e1v[5]=a1q.y; e1v[6]=a1q.z; e1v[7]=a1q.w;
                }
                if (EPI == 2) {
                    float4 b0 = ((const float4*)(e2 + rowbase))[0];
                    float4 b1q = ((const float4*)(e2 + rowbase))[1];
                    e2v[0]=b0.x; e2v[1]=b0.y; e2v[2]=b0.z; e2v[3]=b0.w;
                    e2v[4]=b1q.x; e2v[5]=b1q.y; e2v[6]=b1q.z; e2v[7]=b1q.w;
                }

                int lo = max(j0 - R, 0), hi = min(j0 + R, WW - 1);
                float racc2 = 0.f;
                for (int jj = lo; jj <= hi; ++jj) racc2 += row[swz(jj)];
                float ov[8];
                #pragma unroll
                for (int d = 0; d < 8; ++d) {
                    if (d > 0) {
                        int add = j0 + d + R, sub = j0 + d - R - 1;
                        if (add < WW) racc2 += row[swz(add)];
                        if (sub >= 0) racc2 -= row[swz(sub)];
                    }
                    int j = j0 + d;
                    int cw = min(j + R, WW - 1) - max(j - R, 0) + 1;
                    float chcw = (float)(ch * cw);
                    float r1 = keep1[(p * NSH + si) * 8 + d];
                    float den = fabsf(r1 - racc2) + 1e-4f * chcw;
                    if (EPI == 1) {
                        ov[d] = (fabsf(e1v[d]) * chcw - racc2) / den;
                    } else {
                        ov[d] = ((e1v[d] * chcw - racc2) / den + 0.01f) * e2v[d];
                    }
                }
                float4* d4 = (float4*)&dst[rowbase];
                d4[0] = make_float4(ov[0], ov[1], ov[2], ov[3]);
                d4[1] = make_float4(ov[4], ov[5], ov[6], ov[7]);
            }
        }
    }
}

// ---------------- reduction ----------------
// Pairs element: M holds [Rgx|Lgx|Rgy|Lgy] maps; pair (seg,off) with partner
// at +2^22. n4 = n/4 where n = 2*P16N.
__global__ __launch_bounds__(256) void reduce1(const float* __restrict__ M,
                                               float* __restrict__ partials, int n4) {
    int tid = blockIdx.x * 256 + threadIdx.x;
    float v = 0.f;
    for (int q = tid; q < n4; q += 256 * 1024) {
        int i = q << 2;
        int off = i & ((1 << 22) - 1);
        int seg = i >> 22;                         // 0 -> gx pair, 1 -> gy pair
        size_t aidx = (size_t)seg * (1ull << 23) + (size_t)off;
        float4 a = *(const float4*)(M + aidx);
        float4 b = *(const float4*)(M + aidx + (1u << 22));
        v += a.x * expf(-10.f * (a.x + b.x));
        v += a.y * expf(-10.f * (a.y + b.y));
        v += a.z * expf(-10.f * (a.z + b.z));
        v += a.w * expf(-10.f * (a.w + b.w));
    }
    for (int off = 32; off; off >>= 1) v += __shfl_down(v, off);
    __shared__ float lds[4];
    int lane = threadIdx.x & 63, wv = threadIdx.x >> 6;
    if (lane == 0) lds[wv] = v;
    __syncthreads();
    if (threadIdx.x == 0) partials[blockIdx.x] = lds[0] + lds[1] + lds[2] + lds[3];
}

__global__ __launch_bounds__(256) void reduce2(const float* __restrict__ partials,
                                               float* __restrict__ out, float scale, int n) {
    float v = 0.f;
    for (int i = threadIdx.x; i < n; i += 256) v += partials[i];
    for (int off = 32; off; off >>= 1) v += __shfl_down(v, off);
    __shared__ float lds[4];
    int lane = threadIdx.x & 63, wv = threadIdx.x >> 6;
    if (lane == 0) lds[wv] = v;
    __syncthreads();
    if (threadIdx.x == 0) atomicAdd(out, (lds[0] + lds[1] + lds[2] + lds[3]) * scale);
}

// ---------------- host orchestration ----------------
// Round-1 verified structure (4 stacks, no swizzle, unfused final), kernels
// sub-phased (TH=16 traffic, SUB=8 LDS window).

static void pool_pipeline(float* G, float* A, float* B, float* C, int planes, hipStream_t s) {
    int gp = planes * (HH / 16);
    dual_pool<true , 4, 16, 8><<<gp, 256, 0, s>>>(G, A, B);               // A=max9|g|, B=min9|g|
    davg_pool<8, 1, 16, 8><<<gp, 256, 0, s>>>(A, B, G, nullptr, C);       // C=gn1
    avg_abs_pool<2, 16, 8><<<gp, 256, 0, s>>>(G, A);                      // A=go
    dual_pool<false, 3, 16, 8><<<gp, 256, 0, s>>>(A, B, G);               // B=max7, G=min7
    davg_pool<3, 2, 16, 8><<<gp, 256, 0, s>>>(B, G, A, C, A);             // A=map
}

extern "C" void kernel_launch(void* const* d_in, const int* in_sizes, int n_in,
                              void* d_out, int out_size, void* d_ws, size_t ws_size,
                              hipStream_t stream) {
    const float* Rrgb = (const float*)d_in[0];
    const float* Lrgb = (const float*)d_in[1];
    float* out = (float*)d_out;
    float* w = (float*)d_ws;
    const float scale = 1.f / (float)P16N;
    const int gradblk = (P16N / 4 + 255) / 256;

    hipMemsetAsync(out, 0, sizeof(float) * (size_t)out_size, stream);

    const size_t stack64 = (size_t)64 * SS;
    const size_t stack32 = (size_t)32 * SS;

    if (ws_size >= 4 * stack64 * sizeof(float)) {
        // single pass: 4 buffers of 64 planes [0..16)=Rgx [16..32)=Lgx [32..48)=Rgy [48..64)=Lgy
        float* G = w;
        float* A = G + stack64;
        float* B = A + stack64;
        float* C = B + stack64;
        grad_both<<<gradblk, 256, 0, stream>>>(Rrgb, G, 0, 32, 2);
        grad_both<<<gradblk, 256, 0, stream>>>(Lrgb, G, 16, 48, 2);
        pool_pipeline(G, A, B, C, 64, stream);
        float* partials = C;                      // C dead after map
        reduce1<<<1024, 256, 0, stream>>>(A, partials, (2 * P16N) / 4);
        reduce2<<<1, 256, 0, stream>>>(partials, out, scale, 1024);
    } else {
        // fallback: 4 buffers of 32 planes (128 MiB), one direction at a time
        float* G = w;
        float* A = G + stack32;
        float* B = A + stack32;
        float* C = B + stack32;
        for (int dir = 0; dir < 2; ++dir) {
            grad_both<<<gradblk, 256, 0, stream>>>(Rrgb, G, 0, 0, dir);
            grad_both<<<gradblk, 256, 0, stream>>>(Lrgb, G, 16, 16, dir);
            pool_pipeline(G, A, B, C, 32, stream);
            float* partials = C;
            reduce1<<<1024, 256, 0, stream>>>(A, partials, P16N / 4);
            reduce2<<<1, 256, 0, stream>>>(partials, out, scale, 1024);
        }
    }
}

// Round 7
// 390.897 us; speedup vs baseline: 1.3517x; 1.3517x over previous
//
#include <hip/hip_runtime.h>

#define HH 512
#define WW 512
#define SS (HH * WW)          // elements per plane (2^18)
#define P16N (16 * SS)        // 16 planes (2^22)
#define PADW 576              // skewed LDS row: addr(j) = j + (j>>3)

constexpr float FINF = 3.402823466e38f;

__device__ __forceinline__ int swz(int j) { return j + (j >> 3); }

__device__ __forceinline__ float gray1(float r, float g, float b) {
    return 0.299f * r + 0.587f * g + 0.114f * b;
}

// inverse of small integer c in [R+1, 2R+1] without v_div (cmp+cndmask chain)
template <int R>
__device__ __forceinline__ float invsmall(int c) {
    float r = 1.f / (float)(2 * R + 1);
    #pragma unroll
    for (int v = R + 1; v < 2 * R + 1; ++v)
        if (c == v) r = 1.f / (float)v;      // compile-time constants
    return r;
}

// ---------------- grad (gray fused, both dirs, 4 px/thread) ----------------
__global__ __launch_bounds__(256) void grad_both(const float* __restrict__ rgb,
                                                 float* __restrict__ dst,
                                                 int gxp0, int gyp0, int dirsel) {
    int sp = blockIdx.x * 256 + threadIdx.x;
    int idx = sp << 2;                             // [0, P16N)
    int img = idx >> 18;
    int pix = idx & (SS - 1);
    int i = pix >> 9, j0 = pix & (WW - 1);
    const float* p0 = rgb + (size_t)img * 3 * SS + pix;

    float4 r = *(const float4*)p0;
    float4 g = *(const float4*)(p0 + SS);
    float4 b = *(const float4*)(p0 + 2 * SS);
    float4 gy4 = make_float4(gray1(r.x, g.x, b.x), gray1(r.y, g.y, b.y),
                             gray1(r.z, g.z, b.z), gray1(r.w, g.w, b.w));
    if (dirsel != 1) {
        float grs = 0.f;
        if (j0 + 4 < WW) grs = gray1(p0[4], p0[SS + 4], p0[2 * SS + 4]);
        float4 gx = make_float4(gy4.x - gy4.y, gy4.y - gy4.z, gy4.z - gy4.w, gy4.w - grs);
        *(float4*)(dst + (size_t)(gxp0 + img) * SS + pix) = gx;
    }
    if (dirsel != 0) {
        float4 gd = make_float4(0.f, 0.f, 0.f, 0.f);
        if (i < HH - 1) {
            float4 r2 = *(const float4*)(p0 + WW);
            float4 g2 = *(const float4*)(p0 + SS + WW);
            float4 b2 = *(const float4*)(p0 + 2 * SS + WW);
            gd = make_float4(gray1(r2.x, g2.x, b2.x), gray1(r2.y, g2.y, b2.y),
                             gray1(r2.z, g2.z, b2.z), gray1(r2.w, g2.w, b2.w));
        }
        float4 gy = make_float4(gy4.x - gd.x, gy4.y - gd.y, gy4.z - gd.z, gy4.w - gd.w);
        *(float4*)(dst + (size_t)(gyp0 + img) * SS + pix) = gy;
    }
}

// ---------------- dual max+min pool (column-first, skewed LDS) ----------------
// Round-1 structure; SINGLE ring buffer rb[W] (max and min see the same values;
// out-of-range/stale rows excluded by exact wrap-counted validity mask, all
// compile-time except i0; verified absmax 0 rounds 4-6).
// Phase-split over ONE LDS buffer (36864 B -> 4 blocks/CU):
//   vertical max -> LDS, vertical min -> regs;
//   horizontal max -> dmax; reload regs; horizontal min -> dmin.
template <bool PREABS, int R, int TH>
__global__ __launch_bounds__(256, 4) void dual_pool(const float* __restrict__ src,
                                                    float* __restrict__ dmax,
                                                    float* __restrict__ dmin) {
    constexpr int TILES = HH / TH;
    constexpr int W = 2 * R + 1;
    constexpr int NS = (TH * 64) / 256;
    __shared__ float lbuf[TH * PADW];

    const int plane = blockIdx.x / TILES;
    const int tile  = blockIdx.x % TILES;
    const int i0    = tile * TH;
    const size_t pbase = (size_t)plane * SS;
    const float* sp = src + pbase;
    const int t = threadIdx.x;
    const int ca = swz(2 * t);                     // ca+1 == swz(2t+1)

    float2 rb[W];
    float2 keepmn[TH];
    auto ld = [&](int gi) -> float2 {
        float2 u = ((const float2*)(sp + (size_t)gi * WW))[t];
        if (PREABS) { u.x = fabsf(u.x); u.y = fabsf(u.y); }
        return u;
    };
    #pragma unroll
    for (int k = 0; k < W; ++k)
        if ((unsigned)(i0 - R + k) < (unsigned)HH) rb[k] = ld(i0 - R + k);
    #pragma unroll
    for (int oi = 0; oi < TH; ++oi) {
        if (oi > 0) {
            if ((unsigned)(i0 + oi + R) < (unsigned)HH) rb[(oi - 1) % W] = ld(i0 + oi + R);
        }
        float2 mx = make_float2(-FINF, -FINF), mn = make_float2(FINF, FINF);
        #pragma unroll
        for (int k = 0; k < W; ++k) {
            int wrap = (oi > k) ? ((oi - 1 - k) / W + 1) : 0;   // compile-time
            int ro = k - R + wrap * W;                          // exact row in slot k
            if ((unsigned)(i0 + ro) < (unsigned)HH) {           // block-uniform branch
                mx.x = fmaxf(mx.x, rb[k].x); mx.y = fmaxf(mx.y, rb[k].y);
                mn.x = fminf(mn.x, rb[k].x); mn.y = fminf(mn.y, rb[k].y);
            }
        }
        lbuf[oi * PADW + ca] = mx.x; lbuf[oi * PADW + ca + 1] = mx.y;
        keepmn[oi] = mn;
    }
    __syncthreads();

    // horizontal max -> dmax
    #pragma unroll
    for (int si = 0; si < NS; ++si) {
        int s = si * 256 + t;
        int rr = s >> 6, j0 = (s & 63) << 3;
        const float* rx = &lbuf[rr * PADW];
        float vx[2 * R + 8];
        #pragma unroll
        for (int k = 0; k < 2 * R + 8; ++k) {
            int jj = j0 - R + k;
            bool ok = (unsigned)jj < (unsigned)WW;
            int jc = swz(min(max(jj, 0), WW - 1));
            vx[k] = ok ? rx[jc] : -FINF;
        }
        float ox[8];
        #pragma unroll
        for (int d = 0; d < 8; ++d) {
            float mx = vx[d];
            #pragma unroll
            for (int k = 1; k <= 2 * R; ++k) mx = fmaxf(mx, vx[d + k]);
            ox[d] = mx;
        }
        size_t o = pbase + (size_t)(i0 + rr) * WW + j0;
        ((float4*)&dmax[o])[0] = make_float4(ox[0], ox[1], ox[2], ox[3]);
        ((float4*)&dmax[o])[1] = make_float4(ox[4], ox[5], ox[6], ox[7]);
    }
    __syncthreads();

    // swap in the vertical-min column results
    #pragma unroll
    for (int oi = 0; oi < TH; ++oi) {
        lbuf[oi * PADW + ca] = keepmn[oi].x;
        lbuf[oi * PADW + ca + 1] = keepmn[oi].y;
    }
    __syncthreads();

    // horizontal min -> dmin
    #pragma unroll
    for (int si = 0; si < NS; ++si) {
        int s = si * 256 + t;
        int rr = s >> 6, j0 = (s & 63) << 3;
        const float* rn = &lbuf[rr * PADW];
        float vn[2 * R + 8];
        #pragma unroll
        for (int k = 0; k < 2 * R + 8; ++k) {
            int jj = j0 - R + k;
            bool ok = (unsigned)jj < (unsigned)WW;
            int jc = swz(min(max(jj, 0), WW - 1));
            vn[k] = ok ? rn[jc] : FINF;
        }
        float on[8];
        #pragma unroll
        for (int d = 0; d < 8; ++d) {
            float mn = vn[d];
            #pragma unroll
            for (int k = 1; k <= 2 * R; ++k) mn = fminf(mn, vn[d + k]);
            on[d] = mn;
        }
        size_t o = pbase + (size_t)(i0 + rr) * WW + j0;
        ((float4*)&dmin[o])[0] = make_float4(on[0], on[1], on[2], on[3]);
        ((float4*)&dmin[o])[1] = make_float4(on[4], on[5], on[6], on[7]);
    }
}

// ---------------- single avg pool (abs output), division-free ----------------
template <int R, int TH>
__global__ __launch_bounds__(256, 4) void avg_abs_pool(const float* __restrict__ src,
                                                       float* __restrict__ dst) {
    constexpr int TILES = HH / TH;
    __shared__ float ls[TH * PADW];
    const int plane = blockIdx.x / TILES;
    const int tile  = blockIdx.x % TILES;
    const int i0    = tile * TH;
    const size_t pbase = (size_t)plane * SS;
    const float* sp = src + pbase;
    const int t = threadIdx.x;

    auto ld = [&](int gi) -> float2 {
        if ((unsigned)gi < (unsigned)HH) return ((const float2*)(sp + (size_t)gi * WW))[t];
        return make_float2(0.f, 0.f);
    };
    float2 acc = make_float2(0.f, 0.f);
    #pragma unroll
    for (int k = -R; k <= R; ++k) { float2 v = ld(i0 + k); acc.x += v.x; acc.y += v.y; }
    const int ca = swz(2 * t);
    ls[ca] = acc.x; ls[ca + 1] = acc.y;
    #pragma unroll
    for (int oi = 1; oi < TH; ++oi) {
        float2 a = ld(i0 + oi + R), s = ld(i0 + oi - R - 1);
        acc.x += a.x - s.x; acc.y += a.y - s.y;
        ls[oi * PADW + ca] = acc.x; ls[oi * PADW + ca + 1] = acc.y;
    }
    __syncthreads();

    for (int s = t; s < TH * 64; s += 256) {
        int rr = s >> 6, j0 = (s & 63) << 3;
        int i = i0 + rr;
        int ch = min(i + R, HH - 1) - max(i - R, 0) + 1;
        float invch = invsmall<R>(ch);
        const float* row = &ls[rr * PADW];
        int lo = max(j0 - R, 0), hi = min(j0 + R, WW - 1);
        float racc = 0.f;
        for (int jj = lo; jj <= hi; ++jj) racc += row[swz(jj)];
        float ov[8];
        #pragma unroll
        for (int d = 0; d < 8; ++d) {
            if (d > 0) {
                int add = j0 + d + R, sub = j0 + d - R - 1;
                if (add < WW) racc += row[swz(add)];
                if (sub >= 0) racc -= row[swz(sub)];
            }
            int j = j0 + d;
            int cw = min(j + R, WW - 1) - max(j - R, 0) + 1;
            ov[d] = fabsf(racc * (invch * invsmall<R>(cw)));
        }
        float4* d4 = (float4*)&dst[pbase + (size_t)i * WW + j0];
        d4[0] = make_float4(ov[0], ov[1], ov[2], ov[3]);
        d4[1] = make_float4(ov[4], ov[5], ov[6], ov[7]);
    }
}

// ---------------- dual-input avg pool + combining epilogue ----------------
// v1 = avg(s1), v2 = avg(s2). Division-free form (num & den scaled by ch*cw):
// EPI 1 (gn1): out = (|e1|*chcw - racc2)/(|racc1 - racc2| + 1e-4*chcw)
// EPI 2 (map): out = ((e1*chcw - racc2)/(|racc1 - racc2| + 1e-4*chcw) + 0.01)*e2
// Phase-split over ONE LDS buffer: s1 horizontal sums held in regs (keep1).
// dst may alias e1/e2 (read own pixels before write, same thread).
template <int R, int EPI, int TH>
__global__ __launch_bounds__(256, 4) void davg_pool(const float* __restrict__ s1,
                                                    const float* __restrict__ s2,
                                                    const float* __restrict__ e1,
                                                    const float* __restrict__ e2,
                                                    float* __restrict__ dst) {
    constexpr int TILES = HH / TH;
    constexpr int NS = (TH * 64) / 256;
    __shared__ float lbuf[TH * PADW];
    const int plane = blockIdx.x / TILES;
    const int tile  = blockIdx.x % TILES;
    const int i0    = tile * TH;
    const size_t pbase = (size_t)plane * SS;
    const int t = threadIdx.x;
    const int ca = swz(2 * t);

    auto vert = [&](const float* sp) {
        auto ld = [&](int gi) -> float2 {
            if ((unsigned)gi < (unsigned)HH) return ((const float2*)(sp + (size_t)gi * WW))[t];
            return make_float2(0.f, 0.f);
        };
        float2 acc = make_float2(0.f, 0.f);
        #pragma unroll
        for (int k = -R; k <= R; ++k) { float2 v = ld(i0 + k); acc.x += v.x; acc.y += v.y; }
        lbuf[ca] = acc.x; lbuf[ca + 1] = acc.y;
        #pragma unroll
        for (int oi = 1; oi < TH; ++oi) {
            float2 a = ld(i0 + oi + R), s = ld(i0 + oi - R - 1);
            acc.x += a.x - s.x; acc.y += a.y - s.y;
            lbuf[oi * PADW + ca] = acc.x; lbuf[oi * PADW + ca + 1] = acc.y;
        }
    };

    float keep1[NS * 8];                           // raw horizontal sums of s1

    // ---- phase A: s1 ----
    vert(s1 + pbase);
    __syncthreads();
    #pragma unroll
    for (int si = 0; si < NS; ++si) {
        int s = si * 256 + t;
        int rr = s >> 6, j0 = (s & 63) << 3;
        const float* row = &lbuf[rr * PADW];
        int lo = max(j0 - R, 0), hi = min(j0 + R, WW - 1);
        float racc = 0.f;
        for (int jj = lo; jj <= hi; ++jj) racc += row[swz(jj)];
        #pragma unroll
        for (int d = 0; d < 8; ++d) {
            if (d > 0) {
                int add = j0 + d + R, sub = j0 + d - R - 1;
                if (add < WW) racc += row[swz(add)];
                if (sub >= 0) racc -= row[swz(sub)];
            }
            keep1[si * 8 + d] = racc;
        }
    }
    __syncthreads();

    // ---- phase B: s2 + epilogue ----
    vert(s2 + pbase);
    __syncthreads();
    #pragma unroll
    for (int si = 0; si < NS; ++si) {
        int s = si * 256 + t;
        int rr = s >> 6, j0 = (s & 63) << 3;
        int i = i0 + rr;
        int ch = min(i + R, HH - 1) - max(i - R, 0) + 1;
        const float* row = &lbuf[rr * PADW];
        size_t rowbase = pbase + (size_t)i * WW + j0;

        float e1v[8], e2v[8];
        {
            float4 a0 = ((const float4*)(e1 + rowbase))[0];
            float4 a1q = ((const float4*)(e1 + rowbase))[1];
            e1v[0]=a0.x; e1v[1]=a0.y; e1v[2]=a0.z; e1v[3]=a0.w;
            e1v[4]=a1q.x; e1v[5]=a1q.y; e1v[6]=a1q.z; e1v[7]=a1q.w;
        }
        if (EPI == 2) {
            float4 b0 = ((const float4*)(e2 + rowbase))[0];
            float4 b1q = ((const float4*)(e2 + rowbase))[1];
            e2v[0]=b0.x; e2v[1]=b0.y; e2v[2]=b0.z; e2v[3]=b0.w;
            e2v[4]=b1q.x; e2v[5]=b1q.y; e2v[6]=b1q.z; e2v[7]=b1q.w;
        }

        int lo = max(j0 - R, 0), hi = min(j0 + R, WW - 1);
        float racc2 = 0.f;
        for (int jj = lo; jj <= hi; ++jj) racc2 += row[swz(jj)];
        float ov[8];
        #pragma unroll
        for (int d = 0; d < 8; ++d) {
            if (d > 0) {
                int add = j0 + d + R, sub = j0 + d - R - 1;
                if (add < WW) racc2 += row[swz(add)];
                if (sub >= 0) racc2 -= row[swz(sub)];
            }
            int j = j0 + d;
            int cw = min(j + R, WW - 1) - max(j - R, 0) + 1;
            float chcw = (float)(ch * cw);
            float r1 = keep1[si * 8 + d];
            float den = fabsf(r1 - racc2) + 1e-4f * chcw;
            if (EPI == 1) {
                ov[d] = (fabsf(e1v[d]) * chcw - racc2) / den;
            } else {
                ov[d] = ((e1v[d] * chcw - racc2) / den + 0.01f) * e2v[d];
            }
        }
        float4* d4 = (float4*)&dst[rowbase];
        d4[0] = make_float4(ov[0], ov[1], ov[2], ov[3]);
        d4[1] = make_float4(ov[4], ov[5], ov[6], ov[7]);
    }
}

// ---------------- reduction ----------------
// Pairs element: M holds [Rgx|Lgx|Rgy|Lgy] maps; pair (seg,off) with partner
// at +2^22. n4 = n/4 where n = 2*P16N.
__global__ __launch_bounds__(256) void reduce1(const float* __restrict__ M,
                                               float* __restrict__ partials, int n4) {
    int tid = blockIdx.x * 256 + threadIdx.x;
    float v = 0.f;
    for (int q = tid; q < n4; q += 256 * 1024) {
        int i = q << 2;
        int off = i & ((1 << 22) - 1);
        int seg = i >> 22;                         // 0 -> gx pair, 1 -> gy pair
        size_t aidx = (size_t)seg * (1ull << 23) + (size_t)off;
        float4 a = *(const float4*)(M + aidx);
        float4 b = *(const float4*)(M + aidx + (1u << 22));
        v += a.x * expf(-10.f * (a.x + b.x));
        v += a.y * expf(-10.f * (a.y + b.y));
        v += a.z * expf(-10.f * (a.z + b.z));
        v += a.w * expf(-10.f * (a.w + b.w));
    }
    for (int off = 32; off; off >>= 1) v += __shfl_down(v, off);
    __shared__ float lds[4];
    int lane = threadIdx.x & 63, wv = threadIdx.x >> 6;
    if (lane == 0) lds[wv] = v;
    __syncthreads();
    if (threadIdx.x == 0) partials[blockIdx.x] = lds[0] + lds[1] + lds[2] + lds[3];
}

__global__ __launch_bounds__(256) void reduce2(const float* __restrict__ partials,
                                               float* __restrict__ out, float scale, int n) {
    float v = 0.f;
    for (int i = threadIdx.x; i < n; i += 256) v += partials[i];
    for (int off = 32; off; off >>= 1) v += __shfl_down(v, off);
    __shared__ float lds[4];
    int lane = threadIdx.x & 63, wv = threadIdx.x >> 6;
    if (lane == 0) lds[wv] = v;
    __syncthreads();
    if (threadIdx.x == 0) atomicAdd(out, (lds[0] + lds[1] + lds[2] + lds[3]) * scale);
}

// ---------------- host orchestration (exact round-1 structure) ----------------

static void pool_pipeline(float* G, float* A, float* B, float* C, int planes, hipStream_t s) {
    int gp = planes * (HH / 16);
    dual_pool<true , 4, 16><<<gp, 256, 0, s>>>(G, A, B);                 // A=max9|g|, B=min9|g|
    davg_pool<8, 1, 16><<<gp, 256, 0, s>>>(A, B, G, nullptr, C);         // C=gn1
    avg_abs_pool<2, 16><<<gp, 256, 0, s>>>(G, A);                        // A=go
    dual_pool<false, 3, 16><<<gp, 256, 0, s>>>(A, B, G);                 // B=max7, G=min7
    davg_pool<3, 2, 16><<<gp, 256, 0, s>>>(B, G, A, C, A);               // A=map
}

extern "C" void kernel_launch(void* const* d_in, const int* in_sizes, int n_in,
                              void* d_out, int out_size, void* d_ws, size_t ws_size,
                              hipStream_t stream) {
    const float* Rrgb = (const float*)d_in[0];
    const float* Lrgb = (const float*)d_in[1];
    float* out = (float*)d_out;
    float* w = (float*)d_ws;
    const float scale = 1.f / (float)P16N;
    const int gradblk = (P16N / 4 + 255) / 256;

    hipMemsetAsync(out, 0, sizeof(float) * (size_t)out_size, stream);

    const size_t stack64 = (size_t)64 * SS;
    if (ws_size >= 4 * stack64 * sizeof(float)) {
        // 4 buffers of 64 planes: layout [0..16)=Rgx [16..32)=Lgx [32..48)=Rgy [48..64)=Lgy
        float* G = w;
        float* A = G + stack64;
        float* B = A + stack64;
        float* C = B + stack64;
        grad_both<<<gradblk, 256, 0, stream>>>(Rrgb, G, 0, 32, 2);
        grad_both<<<gradblk, 256, 0, stream>>>(Lrgb, G, 16, 48, 2);
        pool_pipeline(G, A, B, C, 64, stream);
        float* partials = C;                      // C dead after map
        reduce1<<<1024, 256, 0, stream>>>(A, partials, (2 * P16N) / 4);
        reduce2<<<1, 256, 0, stream>>>(partials, out, scale, 1024);
    } else {
        // fallback: 4 buffers of 32 planes (128 MiB), one direction at a time
        const size_t stack32 = (size_t)32 * SS;
        float* G = w;
        float* A = G + stack32;
        float* B = A + stack32;
        float* C = B + stack32;
        for (int dir = 0; dir < 2; ++dir) {
            grad_both<<<gradblk, 256, 0, stream>>>(Rrgb, G, 0, 0, dir);
            grad_both<<<gradblk, 256, 0, stream>>>(Lrgb, G, 16, 16, dir);
            pool_pipeline(G, A, B, C, 32, stream);
            float* partials = C;
            reduce1<<<1024, 256, 0, stream>>>(A, partials, P16N / 4);
            reduce2<<<1, 256, 0, stream>>>(partials, out, scale, 1024);
        }
    }
}